// Round 8
// baseline (206.021 us; speedup 1.0000x reference)
//
#include <hip/hip_runtime.h>
#include <math.h>

typedef short bf16x8 __attribute__((ext_vector_type(8)));
typedef float f32x4  __attribute__((ext_vector_type(4)));

// round-to-nearest-even float -> bf16 bits
__device__ __forceinline__ unsigned short f2bf(float x) {
    unsigned int u = __float_as_uint(x);
    return (unsigned short)((u + 0x7FFFu + ((u >> 16) & 1u)) >> 16);
}
__device__ __forceinline__ float bf2f(unsigned short h) {
    return __uint_as_float(((unsigned int)h) << 16);
}
// RNE split (precompute path)
__device__ __forceinline__ void split2(float x, unsigned short& h, unsigned short& l) {
    h = f2bf(x);
    l = f2bf(x - bf2f(h));
}
// truncation split (hot path): hi = trunc(x), lo = RNE(x - hi); combined rel err ~2^-17
__device__ __forceinline__ void split2t(float x, unsigned short& h, unsigned short& l) {
    unsigned int u = __float_as_uint(x);
    h = (unsigned short)(u >> 16);
    float r = x - __uint_as_float(u & 0xFFFF0000u);
    l = f2bf(r);
}

__device__ __forceinline__ float bperm(int src_lane, float v) {
    return __int_as_float(
        __builtin_amdgcn_ds_bpermute(src_lane << 2, __float_as_int(v)));
}

__device__ __forceinline__ float inv_norm3(float x, float y, float z) {
    float d = fmaf(x, x, fmaf(y, y, z * z));
    return rsqrtf(fmaxf(d, 1e-24f));
}
__device__ __forceinline__ float3 f3sub(float3 a, float3 b) {
    return make_float3(a.x - b.x, a.y - b.y, a.z - b.z);
}
__device__ __forceinline__ float3 f3cross(float3 a, float3 b) {
    return make_float3(a.y * b.z - a.z * b.y,
                       a.z * b.x - a.x * b.z,
                       a.x * b.y - a.y * b.x);
}
__device__ __forceinline__ void nerf_frame(const float3& A, const float3& Bv,
                                           const float3& C, float3& bc,
                                           float3& n, float3& m3) {
    float3 w  = f3sub(C, Bv);
    float3 v  = f3sub(Bv, A);
    float3 cr = f3cross(v, w);
    float iw = inv_norm3(w.x, w.y, w.z);
    float ic = inv_norm3(cr.x, cr.y, cr.z);
    bc = make_float3(w.x * iw, w.y * iw, w.z * iw);
    n  = make_float3(cr.x * ic, cr.y * ic, cr.z * ic);
    m3 = f3cross(n, bc);
}
__device__ __forceinline__ float3 nerf_place(const float3& C, const float3& bc,
                                             const float3& m3, const float3& n,
                                             float tx, float ty, float tz) {
    return make_float3(
        fmaf(m3.x, ty, fmaf(bc.x, tx, fmaf(n.x, tz, C.x))),
        fmaf(m3.y, ty, fmaf(bc.y, tx, fmaf(n.y, tz, C.y))),
        fmaf(m3.z, ty, fmaf(bc.z, tx, fmaf(n.z, tz, C.z))));
}

// ---------- tables (unchanged from r7: MFMA kmer path) ----------
__global__ __launch_bounds__(256) void tables_kernel(
    const float* __restrict__ emb, const float* __restrict__ W0,
    const float* __restrict__ se, const float* __restrict__ b0,
    const float* __restrict__ We, const float* __restrict__ W1,
    float* __restrict__ kt, float* __restrict__ seqT,
    unsigned short* __restrict__ WeTH, unsigned short* __restrict__ WeTL,
    unsigned short* __restrict__ W0pTH, unsigned short* __restrict__ W0pTL,
    unsigned short* __restrict__ W1TH, unsigned short* __restrict__ W1TL) {
    int tid = threadIdx.x;
    if (blockIdx.x < 167) {
        const int lane = tid & 63;
        const int wv   = __builtin_amdgcn_readfirstlane(tid >> 6);
        const int q    = lane >> 4;
        const int c16  = lane & 15;
        const int r0   = blockIdx.x * 64;
        const int n    = wv * 16 + c16;

        bf16x8 BH[8], BL[8];
        #pragma unroll
        for (int kt8 = 0; kt8 < 8; ++kt8)
            #pragma unroll
            for (int j = 0; j < 8; ++j) {
                float w = W0[(16 + kt8 * 32 + q * 8 + j) * 64 + n];
                unsigned short h, l; split2t(w, h, l);
                BH[kt8][j] = (short)h; BL[kt8][j] = (short)l;
            }

        f32x4 acc[4];
        #pragma unroll
        for (int t = 0; t < 4; ++t) acc[t] = (f32x4){0.f, 0.f, 0.f, 0.f};

        #pragma unroll
        for (int kt8 = 0; kt8 < 8; ++kt8) {
            #pragma unroll
            for (int t = 0; t < 4; ++t) {
                int rr = r0 + t * 16 + c16;
                if (rr > 10647) rr = 10647;
                const float* ap = emb + rr * 256 + kt8 * 32 + q * 8;
                float4 a0 = *(const float4*)ap;
                float4 a1 = *(const float4*)(ap + 4);
                bf16x8 ah, al;
                unsigned short h, l;
                split2t(a0.x, h, l); ah[0] = (short)h; al[0] = (short)l;
                split2t(a0.y, h, l); ah[1] = (short)h; al[1] = (short)l;
                split2t(a0.z, h, l); ah[2] = (short)h; al[2] = (short)l;
                split2t(a0.w, h, l); ah[3] = (short)h; al[3] = (short)l;
                split2t(a1.x, h, l); ah[4] = (short)h; al[4] = (short)l;
                split2t(a1.y, h, l); ah[5] = (short)h; al[5] = (short)l;
                split2t(a1.z, h, l); ah[6] = (short)h; al[6] = (short)l;
                split2t(a1.w, h, l); ah[7] = (short)h; al[7] = (short)l;
                acc[t] = __builtin_amdgcn_mfma_f32_16x16x32_bf16(ah, BH[kt8], acc[t], 0, 0, 0);
                acc[t] = __builtin_amdgcn_mfma_f32_16x16x32_bf16(al, BH[kt8], acc[t], 0, 0, 0);
                acc[t] = __builtin_amdgcn_mfma_f32_16x16x32_bf16(ah, BL[kt8], acc[t], 0, 0, 0);
            }
        }
        #pragma unroll
        for (int t = 0; t < 4; ++t)
            #pragma unroll
            for (int r = 0; r < 4; ++r) {
                int row = r0 + t * 16 + q * 4 + r;
                if (row < 10648) kt[row * 64 + n] = acc[t][r];
            }
    } else if (blockIdx.x < 172) {
        int e = (blockIdx.x - 167) * 256 + tid;
        int r = e >> 6, j = e & 63;
        float acc = b0[j];
        #pragma unroll
        for (int k = 0; k < 16; ++k)
            acc = fmaf(se[r * 16 + k], W0[k * 64 + j], acc);
        float cs = 0.f;
        #pragma unroll
        for (int c = 0; c < 21; ++c) cs += W0[(272 + c) * 64 + j];
        seqT[r * 64 + j] = acc + 0.5f * cs;
    } else {
        #pragma unroll
        for (int i = 0; i < 16; ++i) {
            int e = i * 256 + tid;
            int k = e >> 6, n = e & 63;
            unsigned short h, l; split2(We[k * 64 + n], h, l);
            WeTH[n * 64 + k] = h; WeTL[n * 64 + k] = l;
        }
        #pragma unroll
        for (int i = 0; i < 8; ++i) {
            int e = i * 256 + tid;
            int k = e >> 6, n = e & 63;
            float w = (k < 21) ? W0[(272 + k) * 64 + n] : 0.f;
            unsigned short h, l; split2(w, h, l);
            W0pTH[n * 32 + k] = h; W0pTL[n * 32 + k] = l;
        }
        #pragma unroll
        for (int i = 0; i < 4; ++i) {
            int e = i * 256 + tid;
            int k = e >> 4, c = e & 15;
            float w = (c < 9) ? W1[k * 9 + c] : 0.f;
            unsigned short h, l; split2(w, h, l);
            W1TH[c * 64 + k] = h; W1TL[c * 64 + k] = l;
        }
    }
}

// ---------- transposed split-bf16 MFMA MLP: zero LDS, zero barriers ----------
// Every layer computes G = H^T (hid x pos). Wave owns 16 positions; position
// index rides lane&15 through C-layout and B-layout alike. Layer transition
// C->B is an in-wave regroup (hid: 4-per-reg -> 8-per-reg) via ds_bpermute.
// Verified lane algebra: element (j,m): C tile j/16, lane (j%16/4)*16+m, reg j%4;
// B frag kk=j/32, lane ((j%32)/8)*16+m, reg j%8.
__global__ __launch_bounds__(256) void mlp_kernel(
    const int* __restrict__ seq, const int* __restrict__ kmer,
    const float* __restrict__ pssm,
    const float* __restrict__ seqT, const float* __restrict__ kmerT,
    const unsigned short* __restrict__ WeTH, const unsigned short* __restrict__ WeTL,
    const unsigned short* __restrict__ W0pTH, const unsigned short* __restrict__ W0pTL,
    const unsigned short* __restrict__ W1TH, const unsigned short* __restrict__ W1TL,
    const float* __restrict__ be, const float* __restrict__ b1,
    float* __restrict__ srf_t) {

    const int tid  = threadIdx.x;
    const int lane = tid & 63;
    const int wv   = tid >> 6;       // wave id 0..3 (uniform per wave)
    const int qb   = lane >> 4;
    const int m    = lane & 15;
    const int c16  = m;
    const int p    = blockIdx.x * 64 + wv * 16 + m;   // my position
    const int srcbase = ((qb & 1) << 5) + m;          // reshuffle source base

    // ---- C-init: G0[j][m] = seqT[s][j] + kmerT[km][j], j = 16t+4qb+r -> float4s
    const int s  = seq[p];
    const int km = kmer[p];
    f32x4 acc[4];
    #pragma unroll
    for (int t = 0; t < 4; ++t) {
        float4 sv = *(const float4*)(seqT + s * 64 + 16 * t + 4 * qb);
        float4 kv = *(const float4*)(kmerT + km * 64 + 16 * t + 4 * qb);
        acc[t] = (f32x4){sv.x + kv.x, sv.y + kv.y, sv.z + kv.z, sv.w + kv.w};
    }

    // ---- pssm B-fragment: B[k][m] = pssm[p][k]-0.5 (k = 8qb+jj, k<21) ----
    bf16x8 PBH, PBL;
    #pragma unroll
    for (int jj = 0; jj < 8; ++jj) {
        int k = qb * 8 + jj;
        float v = (k < 21) ? (pssm[p * 21 + k] - 0.5f) : 0.f;
        unsigned short h, l; split2t(v, h, l);
        PBH[jj] = (short)h; PBL[jj] = (short)l;
    }

    // ---- layer 0: A = W0p^T frags (from [n][32k] table rows 16t+c16) ----
    #pragma unroll
    for (int t = 0; t < 4; ++t) {
        bf16x8 AH = *(const bf16x8*)(W0pTH + (16 * t + c16) * 32 + qb * 8);
        bf16x8 AL = *(const bf16x8*)(W0pTL + (16 * t + c16) * 32 + qb * 8);
        acc[t] = __builtin_amdgcn_mfma_f32_16x16x32_bf16(AH, PBH, acc[t], 0, 0, 0);
        acc[t] = __builtin_amdgcn_mfma_f32_16x16x32_bf16(AL, PBH, acc[t], 0, 0, 0);
        acc[t] = __builtin_amdgcn_mfma_f32_16x16x32_bf16(AH, PBL, acc[t], 0, 0, 0);
    }

    // ---- preload We^T A-frags (shared by layers 1 and 2; L1-hot) ----
    bf16x8 WeH[4][2], WeL[4][2];
    #pragma unroll
    for (int t = 0; t < 4; ++t)
        #pragma unroll
        for (int kk = 0; kk < 2; ++kk) {
            WeH[t][kk] = *(const bf16x8*)(WeTH + (16 * t + c16) * 64 + kk * 32 + qb * 8);
            WeL[t][kk] = *(const bf16x8*)(WeTL + (16 * t + c16) * 64 + kk * 32 + qb * 8);
        }
    float4 beq[4];
    #pragma unroll
    for (int t = 0; t < 4; ++t)
        beq[t] = *(const float4*)(be + 16 * t + 4 * qb);

    // ---- two hidden layers: reshuffle C->B, then MFMA ----
    #pragma unroll
    for (int layer = 0; layer < 2; ++layer) {
        // build B-frags of current G from acc (C regs)
        bf16x8 GBH[2], GBL[2];
        #pragma unroll
        for (int kk = 0; kk < 2; ++kk) {
            #pragma unroll
            for (int jj = 0; jj < 8; ++jj) {
                int r   = jj & 3;
                int off = (jj >> 2) << 4;
                float va = bperm(srcbase + off, acc[2 * kk][r]);
                float vb = bperm(srcbase + off, acc[2 * kk + 1][r]);
                float g  = (lane & 32) ? vb : va;
                unsigned short h, l; split2t(g, h, l);
                GBH[kk][jj] = (short)h; GBL[kk][jj] = (short)l;
            }
        }
        // acc = be + We^T * G, relu
        #pragma unroll
        for (int t = 0; t < 4; ++t) {
            f32x4 a = (f32x4){beq[t].x, beq[t].y, beq[t].z, beq[t].w};
            #pragma unroll
            for (int kk = 0; kk < 2; ++kk) {
                a = __builtin_amdgcn_mfma_f32_16x16x32_bf16(WeH[t][kk], GBH[kk], a, 0, 0, 0);
                a = __builtin_amdgcn_mfma_f32_16x16x32_bf16(WeL[t][kk], GBH[kk], a, 0, 0, 0);
                a = __builtin_amdgcn_mfma_f32_16x16x32_bf16(WeH[t][kk], GBL[kk], a, 0, 0, 0);
            }
            acc[t] = (f32x4){fmaxf(a[0], 0.f), fmaxf(a[1], 0.f),
                             fmaxf(a[2], 0.f), fmaxf(a[3], 0.f)};
        }
    }

    // ---- head: A = W1^T (1 M-tile of 16 channels), B = G2 frags ----
    {
        bf16x8 GBH[2], GBL[2];
        #pragma unroll
        for (int kk = 0; kk < 2; ++kk) {
            #pragma unroll
            for (int jj = 0; jj < 8; ++jj) {
                int r   = jj & 3;
                int off = (jj >> 2) << 4;
                float va = bperm(srcbase + off, acc[2 * kk][r]);
                float vb = bperm(srcbase + off, acc[2 * kk + 1][r]);
                float g  = (lane & 32) ? vb : va;
                unsigned short h, l; split2t(g, h, l);
                GBH[kk][jj] = (short)h; GBL[kk][jj] = (short)l;
            }
        }
        f32x4 a;
        #pragma unroll
        for (int r = 0; r < 4; ++r) {
            int c = 4 * qb + r;
            a[r] = (c < 9) ? b1[c] : 0.f;
        }
        #pragma unroll
        for (int kk = 0; kk < 2; ++kk) {
            bf16x8 AH = *(const bf16x8*)(W1TH + c16 * 64 + kk * 32 + qb * 8);
            bf16x8 AL = *(const bf16x8*)(W1TL + c16 * 64 + kk * 32 + qb * 8);
            a = __builtin_amdgcn_mfma_f32_16x16x32_bf16(AH, GBH[kk], a, 0, 0, 0);
            a = __builtin_amdgcn_mfma_f32_16x16x32_bf16(AL, GBH[kk], a, 0, 0, 0);
            a = __builtin_amdgcn_mfma_f32_16x16x32_bf16(AH, GBL[kk], a, 0, 0, 0);
        }
        // D[c][m]: c = 4qb+r, position p on lane&15
        const int l = p >> 8, b = p & 255;
        #pragma unroll
        for (int r = 0; r < 4; ++r) {
            int c = 4 * qb + r;
            if (c < 9)
                srf_t[(l * 9 + c) * 256 + b] = a[r];
        }
    }
}

// ---------- pNeRF phase 1: extension, depth-3 prefetch ----------
__global__ __launch_bounds__(64) void extend_kernel(
    const float* __restrict__ srf_t, float* __restrict__ fragbuf,
    float* __restrict__ FPbuf) {
    int frag = blockIdx.x >> 2;
    int bb   = ((blockIdx.x & 3) << 6) + threadIdx.x;

    float3 A  = make_float3(-0.70710678118654752f, 1.22474487139158905f, 0.f);
    float3 Bv = make_float3(-1.41421356237309505f, 0.f, 0.f);
    float3 C  = make_float3(0.f, 0.f, 0.f);

    float ct0[9], ct1[9], ct2[9], ct3[9];
    #pragma unroll
    for (int m = 0; m < 9; ++m) {
        ct0[m] = srf_t[((frag * 32 + 0) * 9 + m) * 256 + bb];
        ct1[m] = srf_t[((frag * 32 + 1) * 9 + m) * 256 + bb];
        ct2[m] = srf_t[((frag * 32 + 2) * 9 + m) * 256 + bb];
    }

    for (int ll = 0; ll < 32; ++ll) {
        if (ll < 29) {
            #pragma unroll
            for (int m = 0; m < 9; ++m)
                ct3[m] = srf_t[((frag * 32 + ll + 3) * 9 + m) * 256 + bb];
        } else {
            #pragma unroll
            for (int m = 0; m < 9; ++m) ct3[m] = 0.f;
        }
        #pragma unroll
        for (int s3 = 0; s3 < 3; ++s3) {
            float3 bc, nn, m3;
            nerf_frame(A, Bv, C, bc, nn, m3);
            float3 d = nerf_place(C, bc, m3, nn,
                                  ct0[3 * s3 + 0], ct0[3 * s3 + 1], ct0[3 * s3 + 2]);
            int row = frag * 96 + ll * 3 + s3;
            fragbuf[(row * 3 + 0) * 256 + bb] = d.x;
            fragbuf[(row * 3 + 1) * 256 + bb] = d.y;
            fragbuf[(row * 3 + 2) * 256 + bb] = d.z;
            A = Bv; Bv = C; C = d;
        }
        #pragma unroll
        for (int m = 0; m < 9; ++m) { ct0[m] = ct1[m]; ct1[m] = ct2[m]; ct2[m] = ct3[m]; }
    }

    float3 bc, nn, m3;
    nerf_frame(A, Bv, C, bc, nn, m3);
    FPbuf[(frag * 12 + 0)  * 256 + bb] = bc.x;
    FPbuf[(frag * 12 + 1)  * 256 + bb] = bc.y;
    FPbuf[(frag * 12 + 2)  * 256 + bb] = bc.z;
    FPbuf[(frag * 12 + 3)  * 256 + bb] = m3.x;
    FPbuf[(frag * 12 + 4)  * 256 + bb] = m3.y;
    FPbuf[(frag * 12 + 5)  * 256 + bb] = m3.z;
    FPbuf[(frag * 12 + 6)  * 256 + bb] = nn.x;
    FPbuf[(frag * 12 + 7)  * 256 + bb] = nn.y;
    FPbuf[(frag * 12 + 8)  * 256 + bb] = nn.z;
    FPbuf[(frag * 12 + 9)  * 256 + bb] = C.x;
    FPbuf[(frag * 12 + 10) * 256 + bb] = C.y;
    FPbuf[(frag * 12 + 11) * 256 + bb] = C.z;
}

// ---------- pNeRF phase 2a: rotation-composition carry (LDS-staged) ----------
__global__ __launch_bounds__(256) void carry_kernel(
    const float* __restrict__ FPbuf, float4* __restrict__ frames) {
    __shared__ float S[384][64];
    int tid  = threadIdx.x;
    int base = blockIdx.x * 64;
    for (int i = tid; i < 384 * 64; i += 256) {
        int row = i >> 6, col = i & 63;
        S[row][col] = FPbuf[row * 256 + base + col];
    }
    __syncthreads();
    if (tid < 64) {
        int bb = base + tid;
        float3 ob = make_float3(1.f, 0.f, 0.f);
        float3 om = make_float3(0.f, 1.f, 0.f);
        float3 on = make_float3(0.f, 0.f, 1.f);
        float3 c  = make_float3(0.f, 0.f, 0.f);
        for (int f = 0; f < 32; ++f) {
            int fb = (f * 256 + bb) * 3;
            frames[fb + 0] = make_float4(ob.x, ob.y, ob.z, om.x);
            frames[fb + 1] = make_float4(om.y, om.z, on.x, on.y);
            frames[fb + 2] = make_float4(on.z, c.x, c.y, c.z);

            int r0 = f * 12;
            float3 Fb = make_float3(S[r0+0][tid], S[r0+1][tid], S[r0+2][tid]);
            float3 Fm = make_float3(S[r0+3][tid], S[r0+4][tid], S[r0+5][tid]);
            float3 Fn = make_float3(S[r0+6][tid], S[r0+7][tid], S[r0+8][tid]);
            float3 p  = make_float3(S[r0+9][tid], S[r0+10][tid], S[r0+11][tid]);

            float3 nb = make_float3(
                fmaf(ob.x,Fb.x, fmaf(om.x,Fb.y, on.x*Fb.z)),
                fmaf(ob.y,Fb.x, fmaf(om.y,Fb.y, on.y*Fb.z)),
                fmaf(ob.z,Fb.x, fmaf(om.z,Fb.y, on.z*Fb.z)));
            float3 nm = make_float3(
                fmaf(ob.x,Fm.x, fmaf(om.x,Fm.y, on.x*Fm.z)),
                fmaf(ob.y,Fm.x, fmaf(om.y,Fm.y, on.y*Fm.z)),
                fmaf(ob.z,Fm.x, fmaf(om.z,Fm.y, on.z*Fm.z)));
            float3 nn = make_float3(
                fmaf(ob.x,Fn.x, fmaf(om.x,Fn.y, on.x*Fn.z)),
                fmaf(ob.y,Fn.x, fmaf(om.y,Fn.y, on.y*Fn.z)),
                fmaf(ob.z,Fn.x, fmaf(om.z,Fn.y, on.z*Fn.z)));
            float3 nc = make_float3(
                fmaf(ob.x,p.x, fmaf(om.x,p.y, fmaf(on.x,p.z, c.x))),
                fmaf(ob.y,p.x, fmaf(om.y,p.y, fmaf(on.y,p.z, c.y))),
                fmaf(ob.z,p.x, fmaf(om.z,p.y, fmaf(on.z,p.z, c.z))));
            ob = nb; om = nm; on = nn; c = nc;
        }
    }
}

// ---------- pNeRF phase 2b: apply frames; LDS-staged coalesced output ----------
__global__ __launch_bounds__(256) void apply_kernel(
    const float* __restrict__ fragbuf, const float4* __restrict__ frames,
    float* __restrict__ out) {
    __shared__ float sm[768];
    int bb   = threadIdx.x;
    int row  = blockIdx.x;
    int frag = row / 96;

    float fx = fragbuf[(row * 3 + 0) * 256 + bb];
    float fy = fragbuf[(row * 3 + 1) * 256 + bb];
    float fz = fragbuf[(row * 3 + 2) * 256 + bb];

    int fb = (frag * 256 + bb) * 3;
    float4 f0 = frames[fb + 0];
    float4 f1 = frames[fb + 1];
    float4 f2 = frames[fb + 2];

    sm[bb * 3 + 0] = f2.y + f0.x * fx + f0.w * fy + f1.z * fz;
    sm[bb * 3 + 1] = f2.z + f0.y * fx + f1.x * fy + f1.w * fz;
    sm[bb * 3 + 2] = f2.w + f0.z * fx + f1.y * fy + f2.x * fz;
    __syncthreads();

    int base = row * 768;
    out[base + bb]       = sm[bb];
    out[base + 256 + bb] = sm[256 + bb];
    out[base + 512 + bb] = sm[512 + bb];
}

// ---------- host launch ----------
extern "C" void kernel_launch(void* const* d_in, const int* in_sizes, int n_in,
                              void* d_out, int out_size, void* d_ws, size_t ws_size,
                              hipStream_t stream) {
    const int*   seq        = (const int*)d_in[0];
    const int*   kmer       = (const int*)d_in[1];
    const float* pssm       = (const float*)d_in[2];
    const float* seq_embed  = (const float*)d_in[4];
    const float* kmer_embed = (const float*)d_in[5];
    const float* W0         = (const float*)d_in[6];
    const float* b0         = (const float*)d_in[7];
    const float* We         = (const float*)d_in[8];
    const float* be         = (const float*)d_in[9];
    const float* W1         = (const float*)d_in[10];
    const float* b1         = (const float*)d_in[11];

    float* ws      = (float*)d_ws;
    float* kmerT   = ws;                       // 10648*64 = 681472
    float* seqT    = kmerT + 681472;           // 1280
    float* srf_t   = seqT + 1280;              // 2359296
    float* fragbuf = srf_t + 2359296;          // 2359296
    float* frames  = fragbuf + 2359296;        // 98304 (float4-accessed)
    float* FPbuf   = frames + 98304;           // 98304
    float* out     = (float*)d_out;

    unsigned short* WeTH  = (unsigned short*)fragbuf;   // aliases fragbuf (safe: mlp before extend)
    unsigned short* WeTL  = WeTH + 4096;
    unsigned short* W0pTH = WeTL + 4096;
    unsigned short* W0pTL = W0pTH + 2048;
    unsigned short* W1TH  = W0pTL + 2048;
    unsigned short* W1TL  = W1TH + 1024;

    hipLaunchKernelGGL(tables_kernel, dim3(173), dim3(256), 0, stream,
                       kmer_embed, W0, seq_embed, b0, We, W1,
                       kmerT, seqT, WeTH, WeTL, W0pTH, W0pTL, W1TH, W1TL);
    hipLaunchKernelGGL(mlp_kernel, dim3(4096), dim3(256), 0, stream,
                       seq, kmer, pssm, seqT, kmerT,
                       WeTH, WeTL, W0pTH, W0pTL, W1TH, W1TL,
                       be, b1, srf_t);
    hipLaunchKernelGGL(extend_kernel, dim3(128), dim3(64), 0, stream,
                       srf_t, fragbuf, FPbuf);
    hipLaunchKernelGGL(carry_kernel, dim3(4), dim3(256), 0, stream,
                       FPbuf, (float4*)frames);
    hipLaunchKernelGGL(apply_kernel, dim3(3072), dim3(256), 0, stream,
                       fragbuf, (float4*)frames, out);
}